// Round 1
// baseline (45.140 us; speedup 1.0000x reference)
//
#include <hip/hip_runtime.h>
#include <hip/hip_bf16.h>

// Problem constants (match reference)
#define NN 1024
#define FF 256
#define DD 64
#define RR 11
#define EE 2048
#define ALPHA 0.2f

// K1: pq[r*F+f] = (dot(W[r,f,:], a[0:64]), dot(W[r,f,:], a[64:128]))
// one wave (64 threads) per (r,f)
__global__ void k1_pq(const float* __restrict__ W, const float* __restrict__ a,
                      float2* __restrict__ pq) {
    int rf = blockIdx.x;            // r*FF + f, < RR*FF
    int lane = threadIdx.x;         // 0..63
    float w = W[(size_t)rf * DD + lane];
    float pa = w * a[lane];
    float qa = w * a[DD + lane];
    #pragma unroll
    for (int o = 32; o > 0; o >>= 1) {
        pa += __shfl_down(pa, o);
        qa += __shfl_down(qa, o);
    }
    if (lane == 0) pq[rf] = make_float2(pa, qa);
}

// K2: et[f*E + e] = leakyrelu(x[src[e],f]*p[rel[e],f] + x[dst[e],f]*q[rel[e],f])
// grid (E/256, F), block 256. Writes transposed (f-major) so K3 is coalesced.
__global__ void k2_score(const float* __restrict__ x, const float2* __restrict__ pq,
                         const int* __restrict__ src, const int* __restrict__ dst,
                         const int* __restrict__ rel, float* __restrict__ et) {
    int e = blockIdx.x * 256 + threadIdx.x;
    int f = blockIdx.y;
    int si = src[e];
    int di = dst[e];
    int r  = rel[e];
    float xs = x[(size_t)si * FF + f];
    float xd = x[(size_t)di * FF + f];
    float2 v = pq[r * FF + f];
    float val = xs * v.x + xd * v.y;
    val = val > 0.0f ? val : ALPHA * val;
    et[(size_t)f * EE + e] = val;
}

// K3: per-feature softmax over the edge axis, in place on et.
// grid F, block 256.
__global__ void k3_softmax(float* __restrict__ et) {
    int f = blockIdx.x;
    float* col = et + (size_t)f * EE;
    int tx = threadIdx.x;
    int wid = tx >> 6, lid = tx & 63;

    float vals[EE / 256];
    float m = -INFINITY;
    #pragma unroll
    for (int k = 0; k < EE / 256; ++k) {
        vals[k] = col[tx + k * 256];
        m = fmaxf(m, vals[k]);
    }
    #pragma unroll
    for (int o = 32; o > 0; o >>= 1) m = fmaxf(m, __shfl_down(m, o));
    __shared__ float sm[4];
    if (lid == 0) sm[wid] = m;
    __syncthreads();
    m = fmaxf(fmaxf(sm[0], sm[1]), fmaxf(sm[2], sm[3]));

    float s = 0.0f;
    #pragma unroll
    for (int k = 0; k < EE / 256; ++k) {
        vals[k] = expf(vals[k] - m);
        s += vals[k];
    }
    #pragma unroll
    for (int o = 32; o > 0; o >>= 1) s += __shfl_down(s, o);
    __shared__ float ss[4];
    if (lid == 0) ss[wid] = s;
    __syncthreads();
    s = ss[0] + ss[1] + ss[2] + ss[3];
    float inv = 1.0f / s;

    #pragma unroll
    for (int k = 0; k < EE / 256; ++k) col[tx + k * 256] = vals[k] * inv;
}

// K4: out[e*D + d] = sum_f attn[f,e] * x[dst[e],f] * W[rel[e],f,d]
// grid E, block 64 (lane = d).
__global__ void k4_out(const float* __restrict__ et, const float* __restrict__ x,
                       const float* __restrict__ W, const int* __restrict__ dst,
                       const int* __restrict__ rel, float* __restrict__ out) {
    int e = blockIdx.x;
    int d = threadIdx.x;            // 0..63
    int di = dst[e];
    int r  = rel[e];
    const float* __restrict__ xrow = x + (size_t)di * FF;
    const float* __restrict__ Wr   = W + (size_t)r * FF * DD;
    float acc = 0.0f;
    #pragma unroll 4
    for (int f = 0; f < FF; ++f) {
        float c = et[(size_t)f * EE + e] * xrow[f];   // uniform (broadcast) loads
        acc = fmaf(c, Wr[f * DD + d], acc);           // coalesced 256B row load
    }
    out[(size_t)e * DD + d] = acc;
}

extern "C" void kernel_launch(void* const* d_in, const int* in_sizes, int n_in,
                              void* d_out, int out_size, void* d_ws, size_t ws_size,
                              hipStream_t stream) {
    const float* x   = (const float*)d_in[0];   // [N, F]
    const float* W   = (const float*)d_in[1];   // [R, F, D]
    const float* a   = (const float*)d_in[2];   // [2*D]
    const int* src   = (const int*)d_in[3];     // [E]
    const int* dst   = (const int*)d_in[4];     // [E]
    const int* rel   = (const int*)d_in[5];     // [E]
    float* out       = (float*)d_out;           // [E*D]

    // workspace layout: et [F*E] floats, then pq [R*F] float2
    float* et  = (float*)d_ws;
    float2* pq = (float2*)((char*)d_ws + (size_t)FF * EE * sizeof(float));

    k1_pq<<<RR * FF, 64, 0, stream>>>(W, a, pq);
    k2_score<<<dim3(EE / 256, FF), 256, 0, stream>>>(x, pq, src, dst, rel, et);
    k3_softmax<<<FF, 256, 0, stream>>>(et);
    k4_out<<<EE, 64, 0, stream>>>(et, x, W, dst, rel, out);
}

// Round 3
// 23.630 us; speedup vs baseline: 1.9103x; 1.9103x over previous
//
#include <hip/hip_runtime.h>
#include <hip/hip_bf16.h>

// Problem constants (match reference)
#define NN 1024
#define FF 256
#define DD 64
#define RR 11
#define EE 2048
#define ALPHA 0.2f
#define TPB 512
#define EPT (EE / TPB)   // 4 edges per thread in K1

// K1: block b owns feature f=b. Compute p[r]=dot(W[r,f,:],a[:64]),
//     q[r]=dot(W[r,f,:],a[64:]); scores for all E edges; softmax over the
//     edge axis; write fused coefficient c[e,f]=attn[e,f]*x[dst[e],f]
//     (e-major so K2 reads contiguously).
__global__ __launch_bounds__(TPB) void k1_coef(
    const float* __restrict__ x, const float* __restrict__ W,
    const float* __restrict__ a, const int* __restrict__ src,
    const int* __restrict__ dst, const int* __restrict__ rel,
    float* __restrict__ cbuf) {

    const int f    = blockIdx.x;   // 0..255
    const int tid  = threadIdx.x;  // 0..511
    const int wid  = tid >> 6;     // 0..7
    const int lane = tid & 63;

    __shared__ float p_sh[RR], q_sh[RR];
    __shared__ float red_m[8], red_s[8];

    // p/q precompute: wave w handles relations r = w, w+8
    for (int r = wid; r < RR; r += 8) {
        float w  = W[((size_t)r * FF + f) * DD + lane];
        float pa = w * a[lane];
        float qa = w * a[DD + lane];
        #pragma unroll
        for (int o = 32; o > 0; o >>= 1) {
            pa += __shfl_down(pa, o);
            qa += __shfl_down(qa, o);
        }
        if (lane == 0) { p_sh[r] = pa; q_sh[r] = qa; }
    }
    __syncthreads();

    // scores for feature f over all edges (4 per thread)
    float vals[EPT], xd_v[EPT];
    float m = -INFINITY;
    #pragma unroll
    for (int k = 0; k < EPT; ++k) {
        int e = tid + k * TPB;
        int si = src[e], di = dst[e], r = rel[e];
        float xs = x[(size_t)si * FF + f];
        float xd = x[(size_t)di * FF + f];
        float v = xs * p_sh[r] + xd * q_sh[r];
        v = v > 0.0f ? v : ALPHA * v;
        vals[k] = v;
        xd_v[k] = xd;
        m = fmaxf(m, v);
    }
    // block-wide max over the edge axis
    #pragma unroll
    for (int o = 32; o > 0; o >>= 1) m = fmaxf(m, __shfl_down(m, o));
    if (lane == 0) red_m[wid] = m;
    __syncthreads();
    m = red_m[0];
    #pragma unroll
    for (int i = 1; i < 8; ++i) m = fmaxf(m, red_m[i]);

    // exp + block-wide sum
    float s = 0.0f;
    #pragma unroll
    for (int k = 0; k < EPT; ++k) {
        vals[k] = expf(vals[k] - m);
        s += vals[k];
    }
    #pragma unroll
    for (int o = 32; o > 0; o >>= 1) s += __shfl_down(s, o);
    if (lane == 0) red_s[wid] = s;
    __syncthreads();
    float st = red_s[0];
    #pragma unroll
    for (int i = 1; i < 8; ++i) st += red_s[i];
    float inv = 1.0f / st;

    // fused coefficient, e-major
    #pragma unroll
    for (int k = 0; k < EPT; ++k) {
        int e = tid + k * TPB;
        cbuf[(size_t)e * FF + f] = vals[k] * inv * xd_v[k];
    }
}

// K2: wave (b,w) owns edge e = b*8+w. out[e,:] = sum_f c[e,f]*W[rel[e],f,:]
//     lane l -> (fgrp=l>>4, dquad=l&15); float4 W loads; shfl_xor reduce.
__global__ __launch_bounds__(TPB) void k2_out(
    const float* __restrict__ W, const int* __restrict__ rel,
    const float* __restrict__ cbuf, float* __restrict__ out) {

    const int tid  = threadIdx.x;
    const int wid  = tid >> 6;
    const int lane = tid & 63;

    int e  = blockIdx.x * 8 + wid;   // 256*8 = 2048 edges
    int r  = rel[e];
    const float* __restrict__ Wr = W + (size_t)r * FF * DD;
    const float* __restrict__ ce = cbuf + (size_t)e * FF;
    int fg = lane >> 4;              // 0..3: f within a 4-group
    int dq = lane & 15;              // 0..15: d-quad
    float4 acc = make_float4(0.f, 0.f, 0.f, 0.f);
    #pragma unroll 8
    for (int fb = 0; fb < FF; fb += 4) {
        int ff = fb + fg;
        float c = ce[ff];                                          // broadcast/16 lanes
        float4 w4 = *(const float4*)&Wr[(size_t)ff * DD + dq * 4]; // 1KB per wave-load
        acc.x = fmaf(c, w4.x, acc.x);
        acc.y = fmaf(c, w4.y, acc.y);
        acc.z = fmaf(c, w4.z, acc.z);
        acc.w = fmaf(c, w4.w, acc.w);
    }
    // sum the 4 f-groups: lanes (l, l^16, l^32, l^48) hold same d-quad
    #pragma unroll
    for (int o = 16; o <= 32; o <<= 1) {
        acc.x += __shfl_xor(acc.x, o);
        acc.y += __shfl_xor(acc.y, o);
        acc.z += __shfl_xor(acc.z, o);
        acc.w += __shfl_xor(acc.w, o);
    }
    if (fg == 0)
        *(float4*)&out[(size_t)e * DD + dq * 4] = acc;
}

extern "C" void kernel_launch(void* const* d_in, const int* in_sizes, int n_in,
                              void* d_out, int out_size, void* d_ws, size_t ws_size,
                              hipStream_t stream) {
    const float* x  = (const float*)d_in[0];   // [N, F]
    const float* W  = (const float*)d_in[1];   // [R, F, D]
    const float* a  = (const float*)d_in[2];   // [2*D]
    const int* src  = (const int*)d_in[3];     // [E]
    const int* dst  = (const int*)d_in[4];     // [E]
    const int* rel  = (const int*)d_in[5];     // [E]
    float* out      = (float*)d_out;           // [E*D]
    float* cbuf     = (float*)d_ws;            // [E*F] fused coefficients

    k1_coef<<<FF, TPB, 0, stream>>>(x, W, a, src, dst, rel, cbuf);
    k2_out<<<EE / 8, TPB, 0, stream>>>(W, rel, cbuf, out);
}